// Round 10
// baseline (346.187 us; speedup 1.0000x reference)
//
#include <hip/hip_runtime.h>
#include <math.h>

#define BB 8
#define NN 2048
#define CC 128
#define KNB 16
#define BN (BB*NN)
#define WPAD 136       // LDS row pad for W (16B-aligned rows, 2-way banks only)

#define EMPTYK 0xFFFFFFFFFFFFFFFFULL

typedef __attribute__((ext_vector_type(8))) short short8;
typedef __attribute__((ext_vector_type(4))) float floatx4;

__device__ __forceinline__ float silu_fast(float x) {
  // x * sigmoid(x); v_exp+v_rcp (~1e-6 rel err, 4 orders below threshold)
  return x * __builtin_amdgcn_rcpf(1.0f + __expf(-x));
}
__device__ __forceinline__ float sqrt_fast(float x) { return __builtin_amdgcn_sqrtf(x); }

__device__ __forceinline__ unsigned long long umin64(unsigned long long a, unsigned long long b) {
  return (b < a) ? b : a;
}

__device__ __forceinline__ unsigned short f2bf(float f) {   // RNE
  unsigned u = __float_as_uint(f);
  unsigned r = u + 0x7FFFu + ((u >> 16) & 1u);
  return (unsigned short)(r >> 16);
}
__device__ __forceinline__ float bf2f(unsigned short s) {
  return __uint_as_float(((unsigned)s) << 16);
}

// ---------------------------------------------------------------------------
// Kernel 1: kNN — one WAVE per query, 4 waves/block, no LDS, no barriers.
// Packed key = (f64(d2) bits & ~2047) | m : u64-monotone on d2, unique,
// lower-index tie-break. Top-4 per lane in regs; rare register-rescan refill.
// ---------------------------------------------------------------------------
__global__ __launch_bounds__(256) void knn_kernel(const float* __restrict__ x,
                                                  int* __restrict__ idx) {
  const int lane = threadIdx.x & 63;
  const int wave = threadIdx.x >> 6;
  const int bn = blockIdx.x * 4 + wave;
  const int b = bn >> 11;
  const int n = bn & (NN - 1);

  const float* xb = x + (size_t)b * NN * 3;
  const double xn0 = (double)xb[n*3+0], xn1 = (double)xb[n*3+1], xn2 = (double)xb[n*3+2];
  const double sqn = xn0*xn0 + xn1*xn1 + xn2*xn2;

  unsigned long long k[32];
  unsigned long long t0 = EMPTYK, t1 = EMPTYK, t2 = EMPTYK, t3 = EMPTYK;

  #pragma unroll
  for (int i = 0; i < 32; ++i) {
    const int m = i*64 + lane;
    const double a0 = (double)xb[m*3+0], a1 = (double)xb[m*3+1], a2 = (double)xb[m*3+2];
    const double sqm = a0*a0 + a1*a1 + a2*a2;
    const double dot = xn0*a0 + xn1*a1 + xn2*a2;
    const double d = sqn + sqm - 2.0*dot;
    unsigned long long kk =
        ((unsigned long long)__double_as_longlong(d) & ~2047ULL) | (unsigned long long)m;
    if (m == n) kk = 0x8000000000000000ULL | (unsigned long long)m;
    k[i] = kk;
    const bool l3 = kk < t3, l2 = kk < t2, l1 = kk < t1, l0 = kk < t0;
    t3 = l3 ? (l2 ? t2 : kk) : t3;
    t2 = l2 ? (l1 ? t1 : kk) : t2;
    t1 = l1 ? (l0 ? t0 : kk) : t1;
    t0 = l0 ? kk : t0;
  }

  int* op = idx + (size_t)bn * KNB;
  for (int t = 0; t < KNB; ++t) {
    unsigned long long g = t0;
    #pragma unroll
    for (int off = 32; off > 0; off >>= 1)
      g = umin64(g, (unsigned long long)__shfl_xor((unsigned long long)g, off, 64));

    if (lane == 0) op[t] = (int)(g & 2047ULL);

    const bool own = (t0 == g);
    t0 = own ? t1 : t0;
    t1 = own ? t2 : t1;
    t2 = own ? t3 : t2;
    t3 = own ? EMPTYK : t3;

    const bool need = (t0 == EMPTYK);
    if (__any(need)) {
      unsigned long long nm = EMPTYK;
      #pragma unroll
      for (int i = 0; i < 32; ++i) {
        const unsigned long long c = (k[i] > g) ? k[i] : EMPTYK;
        nm = umin64(nm, c);
      }
      t0 = need ? nm : t0;
    }
  }
}

// ---------------------------------------------------------------------------
// Kernel 2: Q/K/U via bf16 split-precision MFMA (hi·Whi + lo·Whi + hi·Wlo).
// W hi/lo in LDS; A per-lane from global before the single barrier.
// ---------------------------------------------------------------------------
__global__ __launch_bounds__(256, 2) void vn_gemm_mfma(
    const float* __restrict__ v,
    const float* __restrict__ Wq, const float* __restrict__ Wk, const float* __restrict__ Wu,
    float* __restrict__ Q, float* __restrict__ Kt, float* __restrict__ U)
{
  const int mat = blockIdx.y;
  const float* __restrict__ W = (mat == 0) ? Wq : ((mat == 1) ? Wk : Wu);
  float* __restrict__ Out = (mat == 0) ? Q : ((mat == 1) ? Kt : U);

  __shared__ short Wh[CC][WPAD];
  __shared__ short Wl[CC][WPAD];

  const int tid  = threadIdx.x;
  const int lane = tid & 63;
  const int wave = tid >> 6;
  const int quad = lane >> 4;
  const int l15  = lane & 15;

  const int m = blockIdx.x*64 + wave*16 + l15;
  const int p = m / 3, d = m - 3*p;
  const float* vb = v + (size_t)p * (CC*3) + d;
  float areg[32];
  #pragma unroll
  for (int kc = 0; kc < 4; ++kc)
    #pragma unroll
    for (int j = 0; j < 8; ++j)
      areg[kc*8+j] = vb[(kc*32 + quad*8 + j)*3];

  {
    const float4* Wg = (const float4*)W;
    #pragma unroll
    for (int it = 0; it < 16; ++it) {
      const int i = tid + it*256;
      const int o = i >> 5, c4 = (i & 31) * 4;
      float4 f = Wg[i];
      const float ff[4] = {f.x, f.y, f.z, f.w};
      short hs[4], ls[4];
      #pragma unroll
      for (int q = 0; q < 4; ++q) {
        unsigned short h = f2bf(ff[q]);
        float r = ff[q] - bf2f(h);
        hs[q] = (short)h;
        ls[q] = (short)f2bf(r);
      }
      *(short4*)&Wh[o][c4] = make_short4(hs[0], hs[1], hs[2], hs[3]);
      *(short4*)&Wl[o][c4] = make_short4(ls[0], ls[1], ls[2], ls[3]);
    }
  }

  short8 ah[4], al[4];
  #pragma unroll
  for (int kc = 0; kc < 4; ++kc)
    #pragma unroll
    for (int j = 0; j < 8; ++j) {
      const float f = areg[kc*8+j];
      unsigned short h = f2bf(f);
      float r = f - bf2f(h);
      ah[kc][j] = (short)h;
      al[kc][j] = (short)f2bf(r);
    }
  __syncthreads();

  floatx4 acc[8];
  #pragma unroll
  for (int ct = 0; ct < 8; ++ct) acc[ct] = (floatx4){0.f, 0.f, 0.f, 0.f};

  #pragma unroll
  for (int kc = 0; kc < 4; ++kc) {
    #pragma unroll
    for (int ct = 0; ct < 8; ++ct) {
      const int o = ct*16 + l15;
      const short8 bh = *(const short8*)&Wh[o][kc*32 + quad*8];
      const short8 bl = *(const short8*)&Wl[o][kc*32 + quad*8];
      acc[ct] = __builtin_amdgcn_mfma_f32_16x16x32_bf16(ah[kc], bh, acc[ct], 0, 0, 0);
      acc[ct] = __builtin_amdgcn_mfma_f32_16x16x32_bf16(al[kc], bh, acc[ct], 0, 0, 0);
      acc[ct] = __builtin_amdgcn_mfma_f32_16x16x32_bf16(ah[kc], bl, acc[ct], 0, 0, 0);
    }
  }

  const int r0 = blockIdx.x*64 + wave*16 + quad*4;
  #pragma unroll
  for (int ct = 0; ct < 8; ++ct) {
    const int o = ct*16 + l15;
    #pragma unroll
    for (int reg = 0; reg < 4; ++reg) {
      const int r = r0 + reg;
      const int pp = r / 3, dd = r - 3*pp;
      Out[(size_t)pp * (CC*3) + o*3 + dd] = acc[ct][reg];
    }
  }
}

// ---------------------------------------------------------------------------
// Kernel 3: attention, WAVE-PER-POINT, ZERO barriers.
// Phase A neighbor-major: lane = (t=lane>>2, sub=lane&3); float4 K/Q loads
// over the lane's 32-channel block; dot/kn/qn quad-reduced (2 levels, 3
// payloads — replaces the old 33x6 butterfly). MLP per-lane (4x replicated:
// W1/W2/W3 compile-time uniform -> SGPR operands) with FAST silu
// (v_exp+v_rcp) — the round-9 VALU hog was libm expf + IEEE div.
// Softmax across t (4 xor levels). Phase C channel-major: U gather,
// message, residual, VN-norm (fast sqrt), clamp.
// ---------------------------------------------------------------------------
__global__ __launch_bounds__(256) void attn_wave_kernel(
    const float* __restrict__ x, const int* __restrict__ idx,
    const float* __restrict__ Q, const float* __restrict__ Kt, const float* __restrict__ U,
    const float* __restrict__ W1, const float* __restrict__ b1,
    const float* __restrict__ W2, const float* __restrict__ b2,
    const float* __restrict__ W3, const float* __restrict__ b3,
    const float* __restrict__ gam, const float* __restrict__ bet,
    float* __restrict__ out)
{
  const int lane = threadIdx.x & 63;
  const int wv   = threadIdx.x >> 6;
  const int bn = ((blockIdx.x & 7) << 11) | (((blockIdx.x >> 3) << 2) | wv);
  const int b = bn >> 11;
  const int t   = lane >> 2;    // neighbor
  const int sub = lane & 3;     // 32-channel block

  // own neighbor index (one vector dword load, 4-way shared)
  const int jt = idx[(size_t)bn * KNB + t];

  // ---- Phase A: dot + kn over channels [sub*32,+32); qn partial ----
  const float* Qb = Q  + (size_t)bn * (CC*3) + sub*96;
  const float* Kb = Kt + (size_t)(b*NN + jt) * (CC*3) + sub*96;
  float dacc = 0.f, knacc = 0.f, qnacc = 0.f;
  #pragma unroll
  for (int ch = 0; ch < 8; ++ch) {     // 4 channels (12 floats) per chunk
    const float4 q0 = *(const float4*)(Qb + ch*12);
    const float4 q1 = *(const float4*)(Qb + ch*12 + 4);
    const float4 q2 = *(const float4*)(Qb + ch*12 + 8);
    const float4 k0 = *(const float4*)(Kb + ch*12);
    const float4 k1 = *(const float4*)(Kb + ch*12 + 4);
    const float4 k2 = *(const float4*)(Kb + ch*12 + 8);
    dacc += q0.x*k0.x + q0.y*k0.y + q0.z*k0.z + q0.w*k0.w
          + q1.x*k1.x + q1.y*k1.y + q1.z*k1.z + q1.w*k1.w
          + q2.x*k2.x + q2.y*k2.y + q2.z*k2.z + q2.w*k2.w;
    qnacc += sqrt_fast(q0.x*q0.x + q0.y*q0.y + q0.z*q0.z)
           + sqrt_fast(q0.w*q0.w + q1.x*q1.x + q1.y*q1.y)
           + sqrt_fast(q1.z*q1.z + q1.w*q1.w + q2.x*q2.x)
           + sqrt_fast(q2.y*q2.y + q2.z*q2.z + q2.w*q2.w);
    knacc += sqrt_fast(k0.x*k0.x + k0.y*k0.y + k0.z*k0.z)
           + sqrt_fast(k0.w*k0.w + k1.x*k1.x + k1.y*k1.y)
           + sqrt_fast(k1.z*k1.z + k1.w*k1.w + k2.x*k2.x)
           + sqrt_fast(k2.y*k2.y + k2.z*k2.z + k2.w*k2.w);
  }
  #pragma unroll
  for (int off = 1; off < 4; off <<= 1) {
    dacc  += __shfl_xor(dacc, off, 64);
    knacc += __shfl_xor(knacc, off, 64);
    qnacc += __shfl_xor(qnacc, off, 64);
  }

  // dist feature
  const float xi0 = x[(size_t)bn*3+0], xi1 = x[(size_t)bn*3+1], xi2 = x[(size_t)bn*3+2];
  const float* xj = x + (size_t)(b*NN + jt)*3;
  const float dx = xi0 - xj[0], dy = xi1 - xj[1], dz = xi2 - xj[2];
  const float s0 = qnacc * (1.0f/128.0f);
  const float s1 = knacc * (1.0f/128.0f);
  const float s2 = dacc  * (1.0f/128.0f);
  const float s3 = sqrt_fast(dx*dx + dy*dy + dz*dz);

  // ---- Phase B: edge MLP (scalar weights, fast silu) ----
  float h1[32];
  #pragma unroll
  for (int h = 0; h < 32; ++h) {
    const float u = b1[h] + W1[h*4+0]*s0 + W1[h*4+1]*s1 + W1[h*4+2]*s2 + W1[h*4+3]*s3;
    h1[h] = silu_fast(u);
  }
  float logit = b3[0];
  #pragma unroll
  for (int h = 0; h < 32; ++h) {
    float a = b2[h];
    #pragma unroll
    for (int c = 0; c < 32; ++c) a = fmaf(W2[h*32+c], h1[c], a);
    logit = fmaf(W3[h], silu_fast(a), logit);
  }
  logit = fminf(fmaxf(logit, -10.0f), 10.0f);

  // softmax across the 16 neighbors (xor levels 4..32; quad-mates redundant)
  float mx = logit;
  #pragma unroll
  for (int off = 4; off < 64; off <<= 1) mx = fmaxf(mx, __shfl_xor(mx, off, 64));
  const float e = __expf(logit - mx);
  float ssum = e;
  #pragma unroll
  for (int off = 4; off < 64; off <<= 1) ssum += __shfl_xor(ssum, off, 64);
  const float w = e * __builtin_amdgcn_rcpf(ssum);

  // broadcast the 16 weights (lane 4*t holds neighbor t's weight)
  float wk[KNB];
  #pragma unroll
  for (int t2 = 0; t2 < KNB; ++t2) wk[t2] = __shfl(w, t2*4, 64);

  // ---- Phase C: channel-major message + residual + VN norm + clamp ----
  const int* ip = idx + (size_t)bn * KNB;
  float m0=0.f,m1=0.f,m2=0.f,m3=0.f,m4=0.f,m5=0.f;
  #pragma unroll
  for (int t2 = 0; t2 < KNB; ++t2) {
    const float* Up = U + (size_t)(b*NN + ip[t2]) * (CC*3) + lane*6;
    const float2 a = *(const float2*)Up;
    const float2 bb = *(const float2*)(Up+2);
    const float2 c = *(const float2*)(Up+4);
    const float ww = wk[t2];
    m0 = fmaf(ww, a.x, m0);  m1 = fmaf(ww, a.y, m1);  m2 = fmaf(ww, bb.x, m2);
    m3 = fmaf(ww, bb.y, m3); m4 = fmaf(ww, c.x, m4);  m5 = fmaf(ww, c.y, m5);
  }
  const float* Qc = Q + (size_t)bn * (CC*3) + lane*6;
  const float2 qa = *(const float2*)Qc;
  const float2 qb = *(const float2*)(Qc+2);
  const float2 qc = *(const float2*)(Qc+4);
  const float oa0 = qa.x + 0.5f*m0, oa1 = qa.y + 0.5f*m1, oa2 = qb.x + 0.5f*m2;
  const float ob0 = qb.y + 0.5f*m3, ob1 = qc.x + 0.5f*m4, ob2 = qc.y + 0.5f*m5;

  const float na = fmaxf(sqrt_fast(oa0*oa0 + oa1*oa1 + oa2*oa2), 1e-6f);
  const float nb = fmaxf(sqrt_fast(ob0*ob0 + ob1*ob1 + ob2*ob2), 1e-6f);
  float s = na + nb;
  #pragma unroll
  for (int off = 1; off < 64; off <<= 1) s += __shfl_xor(s, off, 64);
  const float mean = s * (1.0f/128.0f);
  const float dva = na - mean, dvb = nb - mean;
  float s2v = dva*dva + dvb*dvb;
  #pragma unroll
  for (int off = 1; off < 64; off <<= 1) s2v += __shfl_xor(s2v, off, 64);
  const float stdv = fmaxf(sqrt_fast(s2v * (1.0f/127.0f)), 1e-6f);

  const float2 gm = *(const float2*)(gam + lane*2);
  const float2 bt = *(const float2*)(bet + lane*2);
  const float nsa = (na - mean) / stdv * gm.x + bt.x;
  const float nsb = (nb - mean) / stdv * gm.y + bt.y;
  const float sca = fmaxf(nsa, 1e-6f) / na;
  const float scb = fmaxf(nsb, 1e-6f) / nb;
  float fa0 = oa0*sca, fa1 = oa1*sca, fa2 = oa2*sca;
  float fb0 = ob0*scb, fb1 = ob1*scb, fb2 = ob2*scb;
  const float n2a = fmaxf(sqrt_fast(fa0*fa0 + fa1*fa1 + fa2*fa2), 1e-6f);
  const float n2b = fmaxf(sqrt_fast(fb0*fb0 + fb1*fb1 + fb2*fb2), 1e-6f);
  const float c2a = fminf(50.0f / n2a, 1.0f);
  const float c2b = fminf(50.0f / n2b, 1.0f);

  float* op = out + (size_t)bn * (CC*3) + lane*6;
  *(float2*)op     = make_float2(fa0*c2a, fa1*c2a);
  *(float2*)(op+2) = make_float2(fa2*c2a, fb0*c2b);
  *(float2*)(op+4) = make_float2(fb1*c2b, fb2*c2b);
}

// ---------------------------------------------------------------------------
extern "C" void kernel_launch(void* const* d_in, const int* in_sizes, int n_in,
                              void* d_out, int out_size, void* d_ws, size_t ws_size,
                              hipStream_t stream) {
  (void)in_sizes; (void)n_in; (void)out_size; (void)ws_size;
  const float* x   = (const float*)d_in[0];
  const float* v   = (const float*)d_in[1];
  const float* Wq  = (const float*)d_in[2];
  const float* Wk  = (const float*)d_in[3];
  const float* Wu  = (const float*)d_in[4];
  const float* W1  = (const float*)d_in[5];
  const float* b1  = (const float*)d_in[6];
  const float* W2  = (const float*)d_in[7];
  const float* b2  = (const float*)d_in[8];
  const float* W3  = (const float*)d_in[9];
  const float* b3  = (const float*)d_in[10];
  const float* gam = (const float*)d_in[11];
  const float* bet = (const float*)d_in[12];
  float* out = (float*)d_out;

  char* ws = (char*)d_ws;
  int*   idx = (int*)ws;                                  // BN*16 ints (1 MB)
  float* Q   = (float*)(ws + (size_t)BN * KNB * 4);       // BN*384 floats
  float* Kt  = Q  + (size_t)BN * CC * 3;
  float* U   = Kt + (size_t)BN * CC * 3;

  knn_kernel<<<BN/4, 256, 0, stream>>>(x, idx);
  vn_gemm_mfma<<<dim3((BN*3)/64, 3), 256, 0, stream>>>(v, Wq, Wk, Wu, Q, Kt, U);
  attn_wave_kernel<<<BN/4, 256, 0, stream>>>(x, idx, Q, Kt, U,
                                             W1, b1, W2, b2, W3, b3, gam, bet, out);
}

// Round 11
// 334.715 us; speedup vs baseline: 1.0343x; 1.0343x over previous
//
#include <hip/hip_runtime.h>
#include <math.h>

#define BB 8
#define NN 2048
#define CC 128
#define KNB 16
#define BN (BB*NN)
#define WPAD 136       // LDS row pad for W (16B-aligned rows, 2-way banks only)

#define EMPTYK 0xFFFFFFFFFFFFFFFFULL

typedef __attribute__((ext_vector_type(8))) short short8;
typedef __attribute__((ext_vector_type(4))) float floatx4;

__device__ __forceinline__ float silu_fast(float x) {
  return x * __builtin_amdgcn_rcpf(1.0f + __expf(-x));
}
__device__ __forceinline__ float sqrt_fast(float x) { return __builtin_amdgcn_sqrtf(x); }

__device__ __forceinline__ unsigned long long umin64(unsigned long long a, unsigned long long b) {
  return (b < a) ? b : a;
}

__device__ __forceinline__ unsigned short f2bf(float f) {   // RNE
  unsigned u = __float_as_uint(f);
  unsigned r = u + 0x7FFFu + ((u >> 16) & 1u);
  return (unsigned short)(r >> 16);
}
__device__ __forceinline__ float bf2f(unsigned short s) {
  return __uint_as_float(((unsigned)s) << 16);
}

// ---------------------------------------------------------------------------
// Kernel 1: kNN — one WAVE per query, 4 waves/block, no LDS, no barriers.
// ---------------------------------------------------------------------------
__global__ __launch_bounds__(256) void knn_kernel(const float* __restrict__ x,
                                                  int* __restrict__ idx) {
  const int lane = threadIdx.x & 63;
  const int wave = threadIdx.x >> 6;
  const int bn = blockIdx.x * 4 + wave;
  const int b = bn >> 11;
  const int n = bn & (NN - 1);

  const float* xb = x + (size_t)b * NN * 3;
  const double xn0 = (double)xb[n*3+0], xn1 = (double)xb[n*3+1], xn2 = (double)xb[n*3+2];
  const double sqn = xn0*xn0 + xn1*xn1 + xn2*xn2;

  unsigned long long k[32];
  unsigned long long t0 = EMPTYK, t1 = EMPTYK, t2 = EMPTYK, t3 = EMPTYK;

  #pragma unroll
  for (int i = 0; i < 32; ++i) {
    const int m = i*64 + lane;
    const double a0 = (double)xb[m*3+0], a1 = (double)xb[m*3+1], a2 = (double)xb[m*3+2];
    const double sqm = a0*a0 + a1*a1 + a2*a2;
    const double dot = xn0*a0 + xn1*a1 + xn2*a2;
    const double d = sqn + sqm - 2.0*dot;
    unsigned long long kk =
        ((unsigned long long)__double_as_longlong(d) & ~2047ULL) | (unsigned long long)m;
    if (m == n) kk = 0x8000000000000000ULL | (unsigned long long)m;
    k[i] = kk;
    const bool l3 = kk < t3, l2 = kk < t2, l1 = kk < t1, l0 = kk < t0;
    t3 = l3 ? (l2 ? t2 : kk) : t3;
    t2 = l2 ? (l1 ? t1 : kk) : t2;
    t1 = l1 ? (l0 ? t0 : kk) : t1;
    t0 = l0 ? kk : t0;
  }

  int* op = idx + (size_t)bn * KNB;
  for (int t = 0; t < KNB; ++t) {
    unsigned long long g = t0;
    #pragma unroll
    for (int off = 32; off > 0; off >>= 1)
      g = umin64(g, (unsigned long long)__shfl_xor((unsigned long long)g, off, 64));

    if (lane == 0) op[t] = (int)(g & 2047ULL);

    const bool own = (t0 == g);
    t0 = own ? t1 : t0;
    t1 = own ? t2 : t1;
    t2 = own ? t3 : t2;
    t3 = own ? EMPTYK : t3;

    const bool need = (t0 == EMPTYK);
    if (__any(need)) {
      unsigned long long nm = EMPTYK;
      #pragma unroll
      for (int i = 0; i < 32; ++i) {
        const unsigned long long c = (k[i] > g) ? k[i] : EMPTYK;
        nm = umin64(nm, c);
      }
      t0 = need ? nm : t0;
    }
  }
}

// ---------------------------------------------------------------------------
// Kernel 2: Q/K/U via bf16 split-precision MFMA (hi·Whi + lo·Whi + hi·Wlo).
// ---------------------------------------------------------------------------
__global__ __launch_bounds__(256, 2) void vn_gemm_mfma(
    const float* __restrict__ v,
    const float* __restrict__ Wq, const float* __restrict__ Wk, const float* __restrict__ Wu,
    float* __restrict__ Q, float* __restrict__ Kt, float* __restrict__ U)
{
  const int mat = blockIdx.y;
  const float* __restrict__ W = (mat == 0) ? Wq : ((mat == 1) ? Wk : Wu);
  float* __restrict__ Out = (mat == 0) ? Q : ((mat == 1) ? Kt : U);

  __shared__ short Wh[CC][WPAD];
  __shared__ short Wl[CC][WPAD];

  const int tid  = threadIdx.x;
  const int lane = tid & 63;
  const int wave = tid >> 6;
  const int quad = lane >> 4;
  const int l15  = lane & 15;

  const int m = blockIdx.x*64 + wave*16 + l15;
  const int p = m / 3, d = m - 3*p;
  const float* vb = v + (size_t)p * (CC*3) + d;
  float areg[32];
  #pragma unroll
  for (int kc = 0; kc < 4; ++kc)
    #pragma unroll
    for (int j = 0; j < 8; ++j)
      areg[kc*8+j] = vb[(kc*32 + quad*8 + j)*3];

  {
    const float4* Wg = (const float4*)W;
    #pragma unroll
    for (int it = 0; it < 16; ++it) {
      const int i = tid + it*256;
      const int o = i >> 5, c4 = (i & 31) * 4;
      float4 f = Wg[i];
      const float ff[4] = {f.x, f.y, f.z, f.w};
      short hs[4], ls[4];
      #pragma unroll
      for (int q = 0; q < 4; ++q) {
        unsigned short h = f2bf(ff[q]);
        float r = ff[q] - bf2f(h);
        hs[q] = (short)h;
        ls[q] = (short)f2bf(r);
      }
      *(short4*)&Wh[o][c4] = make_short4(hs[0], hs[1], hs[2], hs[3]);
      *(short4*)&Wl[o][c4] = make_short4(ls[0], ls[1], ls[2], ls[3]);
    }
  }

  short8 ah[4], al[4];
  #pragma unroll
  for (int kc = 0; kc < 4; ++kc)
    #pragma unroll
    for (int j = 0; j < 8; ++j) {
      const float f = areg[kc*8+j];
      unsigned short h = f2bf(f);
      float r = f - bf2f(h);
      ah[kc][j] = (short)h;
      al[kc][j] = (short)f2bf(r);
    }
  __syncthreads();

  floatx4 acc[8];
  #pragma unroll
  for (int ct = 0; ct < 8; ++ct) acc[ct] = (floatx4){0.f, 0.f, 0.f, 0.f};

  #pragma unroll
  for (int kc = 0; kc < 4; ++kc) {
    #pragma unroll
    for (int ct = 0; ct < 8; ++ct) {
      const int o = ct*16 + l15;
      const short8 bh = *(const short8*)&Wh[o][kc*32 + quad*8];
      const short8 bl = *(const short8*)&Wl[o][kc*32 + quad*8];
      acc[ct] = __builtin_amdgcn_mfma_f32_16x16x32_bf16(ah[kc], bh, acc[ct], 0, 0, 0);
      acc[ct] = __builtin_amdgcn_mfma_f32_16x16x32_bf16(al[kc], bh, acc[ct], 0, 0, 0);
      acc[ct] = __builtin_amdgcn_mfma_f32_16x16x32_bf16(ah[kc], bl, acc[ct], 0, 0, 0);
    }
  }

  const int r0 = blockIdx.x*64 + wave*16 + quad*4;
  #pragma unroll
  for (int ct = 0; ct < 8; ++ct) {
    const int o = ct*16 + l15;
    #pragma unroll
    for (int reg = 0; reg < 4; ++reg) {
      const int r = r0 + reg;
      const int pp = r / 3, dd = r - 3*pp;
      Out[(size_t)pp * (CC*3) + o*3 + dd] = acc[ct][reg];
    }
  }
}

// ---------------------------------------------------------------------------
// Kernel 2b: qn/kn = mean over o of ||Q[p,o,:]|| (and K). One wave per point.
// ---------------------------------------------------------------------------
__global__ __launch_bounds__(256) void norms_kernel(
    const float* __restrict__ Q, const float* __restrict__ Kt,
    float* __restrict__ qn, float* __restrict__ kn)
{
  const int lane = threadIdx.x & 63;
  const int pnt = blockIdx.x * 4 + (threadIdx.x >> 6);

  const float* Qp = Q + (size_t)pnt * (CC*3) + lane*6;
  float s = 0.f;
  {
    const float x0=Qp[0],x1=Qp[1],x2=Qp[2],x3=Qp[3],x4=Qp[4],x5=Qp[5];
    s = sqrtf(x0*x0+x1*x1+x2*x2) + sqrtf(x3*x3+x4*x4+x5*x5);
  }
  #pragma unroll
  for (int off = 32; off > 0; off >>= 1) s += __shfl_xor(s, off, 64);
  if (lane == 0) qn[pnt] = s * (1.0f/128.0f);

  const float* Kp = Kt + (size_t)pnt * (CC*3) + lane*6;
  float s2 = 0.f;
  {
    const float x0=Kp[0],x1=Kp[1],x2=Kp[2],x3=Kp[3],x4=Kp[4],x5=Kp[5];
    s2 = sqrtf(x0*x0+x1*x1+x2*x2) + sqrtf(x3*x3+x4*x4+x5*x5);
  }
  #pragma unroll
  for (int off = 32; off > 0; off >>= 1) s2 += __shfl_xor(s2, off, 64);
  if (lane == 0) kn[pnt] = s2 * (1.0f/128.0f);
}

// ---------------------------------------------------------------------------
// Kernel 3: attention, EDGE-PER-LANE: wave = 4 points x 16 edges; zero
// barriers; MLP at 1x redundancy (weights wave-uniform -> SGPR operands);
// qn/kn precomputed (no sqrt chains in phase A). Phase C: lane = (pt,
// channel-group of 8); float4 U gathers; width-16 reductions.
// ---------------------------------------------------------------------------
__global__ __launch_bounds__(256, 4) void attn_edge_kernel(
    const float* __restrict__ x, const int* __restrict__ idx,
    const float* __restrict__ Q, const float* __restrict__ Kt, const float* __restrict__ U,
    const float* __restrict__ qn, const float* __restrict__ kn,
    const float* __restrict__ W1, const float* __restrict__ b1,
    const float* __restrict__ W2, const float* __restrict__ b2,
    const float* __restrict__ W3, const float* __restrict__ b3,
    const float* __restrict__ gam, const float* __restrict__ bet,
    float* __restrict__ out)
{
  const int lane = threadIdx.x & 63;
  const int wv   = threadIdx.x >> 6;
  const int pt = lane >> 4;          // point within wave (0..3)
  const int e  = lane & 15;          // neighbor (phase A/B) / channel group (phase C)
  const int bbatch = blockIdx.x & 7; // XCD swizzle: batch = blockIdx%8
  const int grp = ((int)blockIdx.x >> 3) * 16 + wv*4 + pt;   // point in batch
  const int bn = (bbatch << 11) | grp;
  const int b = bbatch;

  // edge (bn, jt): idx loads are lane-consecutive (coalesced)
  const int jt = idx[(size_t)bn * KNB + e];

  // ---- Phase A: full Q.K dot per lane (Q stream shared by 16 lanes -> L1) --
  const float4* Qb = (const float4*)(Q + (size_t)bn * (CC*3));
  const float4* Kb = (const float4*)(Kt + (size_t)(b*NN + jt) * (CC*3));
  float dacc = 0.f;
  #pragma unroll 8
  for (int i = 0; i < 96; ++i) {
    const float4 q4 = Qb[i];
    const float4 k4 = Kb[i];
    dacc += q4.x*k4.x + q4.y*k4.y + q4.z*k4.z + q4.w*k4.w;
  }

  // features
  const float xi0 = x[(size_t)bn*3+0], xi1 = x[(size_t)bn*3+1], xi2 = x[(size_t)bn*3+2];
  const float* xj = x + (size_t)(b*NN + jt)*3;
  const float dx = xi0 - xj[0], dy = xi1 - xj[1], dz = xi2 - xj[2];
  const float s0 = qn[bn];
  const float s1 = kn[b*NN + jt];
  const float s2 = dacc * (1.0f/128.0f);
  const float s3 = sqrt_fast(dx*dx + dy*dy + dz*dz);

  // ---- Phase B: edge MLP, one edge per lane (uniform weights -> s_load) ----
  float h1[32];
  #pragma unroll
  for (int h = 0; h < 32; ++h) {
    const float u = b1[h] + W1[h*4+0]*s0 + W1[h*4+1]*s1 + W1[h*4+2]*s2 + W1[h*4+3]*s3;
    h1[h] = silu_fast(u);
  }
  float logit = b3[0];
  #pragma unroll
  for (int h = 0; h < 32; ++h) {
    float a = b2[h];
    #pragma unroll
    for (int c = 0; c < 32; ++c) a = fmaf(W2[h*32+c], h1[c], a);
    logit = fmaf(W3[h], silu_fast(a), logit);
  }
  logit = fminf(fmaxf(logit, -10.0f), 10.0f);

  // softmax within the 16-lane point group
  float mx = logit;
  #pragma unroll
  for (int off = 8; off > 0; off >>= 1) mx = fmaxf(mx, __shfl_xor(mx, off, 16));
  const float ev = __expf(logit - mx);
  float ssum = ev;
  #pragma unroll
  for (int off = 8; off > 0; off >>= 1) ssum += __shfl_xor(ssum, off, 16);
  const float w = ev * __builtin_amdgcn_rcpf(ssum);

  // ---- Phase C: broadcast group weights/indices; channel-group message ----
  const int gbase = lane & 48;
  float wk[KNB]; int jj[KNB];
  #pragma unroll
  for (int t = 0; t < KNB; ++t) {
    wk[t] = __shfl(w, gbase + t, 64);
    jj[t] = __shfl(jt, gbase + t, 64);
  }

  // lane covers channels [e*8, e*8+8) = floats [e*24, e*24+24)
  float acc[24];
  #pragma unroll
  for (int i = 0; i < 24; ++i) acc[i] = 0.f;
  #pragma unroll
  for (int t = 0; t < KNB; ++t) {
    const float4* Up = (const float4*)(U + (size_t)(b*NN + jj[t]) * (CC*3) + e*24);
    const float ww = wk[t];
    #pragma unroll
    for (int i = 0; i < 6; ++i) {
      const float4 u4 = Up[i];
      acc[i*4+0] = fmaf(ww, u4.x, acc[i*4+0]);
      acc[i*4+1] = fmaf(ww, u4.y, acc[i*4+1]);
      acc[i*4+2] = fmaf(ww, u4.z, acc[i*4+2]);
      acc[i*4+3] = fmaf(ww, u4.w, acc[i*4+3]);
    }
  }

  // residual
  const float4* Qc = (const float4*)(Q + (size_t)bn * (CC*3) + e*24);
  float o6[24];
  #pragma unroll
  for (int i = 0; i < 6; ++i) {
    const float4 q4 = Qc[i];
    o6[i*4+0] = q4.x + 0.5f*acc[i*4+0];
    o6[i*4+1] = q4.y + 0.5f*acc[i*4+1];
    o6[i*4+2] = q4.z + 0.5f*acc[i*4+2];
    o6[i*4+3] = q4.w + 0.5f*acc[i*4+3];
  }

  // VN layer norm over 128 channels (8 per lane, width-16 reduce)
  float nc[8];
  float s = 0.f;
  #pragma unroll
  for (int c = 0; c < 8; ++c) {
    const float a0 = o6[c*3+0], a1 = o6[c*3+1], a2 = o6[c*3+2];
    nc[c] = fmaxf(sqrt_fast(a0*a0 + a1*a1 + a2*a2), 1e-6f);
    s += nc[c];
  }
  #pragma unroll
  for (int off = 8; off > 0; off >>= 1) s += __shfl_xor(s, off, 16);
  const float mean = s * (1.0f/128.0f);
  float s2v = 0.f;
  #pragma unroll
  for (int c = 0; c < 8; ++c) { const float d2 = nc[c] - mean; s2v += d2*d2; }
  #pragma unroll
  for (int off = 8; off > 0; off >>= 1) s2v += __shfl_xor(s2v, off, 16);
  const float stdv = fmaxf(sqrt_fast(s2v * (1.0f/127.0f)), 1e-6f);
  const float rstd = __builtin_amdgcn_rcpf(stdv);

  const float4* gm4 = (const float4*)(gam + e*8);
  const float4* bt4 = (const float4*)(bet + e*8);
  const float4 g0 = gm4[0], g1 = gm4[1];
  const float4 bt0 = bt4[0], bt1 = bt4[1];
  const float gmv[8] = {g0.x,g0.y,g0.z,g0.w,g1.x,g1.y,g1.z,g1.w};
  const float btv[8] = {bt0.x,bt0.y,bt0.z,bt0.w,bt1.x,bt1.y,bt1.z,bt1.w};

  float res[24];
  #pragma unroll
  for (int c = 0; c < 8; ++c) {
    const float ns = (nc[c] - mean) * rstd * gmv[c] + btv[c];
    const float sc1 = fmaxf(ns, 1e-6f) * __builtin_amdgcn_rcpf(nc[c]);
    float f0 = o6[c*3+0]*sc1, f1 = o6[c*3+1]*sc1, f2 = o6[c*3+2]*sc1;
    const float n2 = fmaxf(sqrt_fast(f0*f0 + f1*f1 + f2*f2), 1e-6f);
    const float sc2 = fminf(50.0f * __builtin_amdgcn_rcpf(n2), 1.0f);
    res[c*3+0] = f0*sc2; res[c*3+1] = f1*sc2; res[c*3+2] = f2*sc2;
  }

  float4* op = (float4*)(out + (size_t)bn * (CC*3) + e*24);
  #pragma unroll
  for (int i = 0; i < 6; ++i)
    op[i] = make_float4(res[i*4+0], res[i*4+1], res[i*4+2], res[i*4+3]);
}

// ---------------------------------------------------------------------------
extern "C" void kernel_launch(void* const* d_in, const int* in_sizes, int n_in,
                              void* d_out, int out_size, void* d_ws, size_t ws_size,
                              hipStream_t stream) {
  (void)in_sizes; (void)n_in; (void)out_size; (void)ws_size;
  const float* x   = (const float*)d_in[0];
  const float* v   = (const float*)d_in[1];
  const float* Wq  = (const float*)d_in[2];
  const float* Wk  = (const float*)d_in[3];
  const float* Wu  = (const float*)d_in[4];
  const float* W1  = (const float*)d_in[5];
  const float* b1  = (const float*)d_in[6];
  const float* W2  = (const float*)d_in[7];
  const float* b2  = (const float*)d_in[8];
  const float* W3  = (const float*)d_in[9];
  const float* b3  = (const float*)d_in[10];
  const float* gam = (const float*)d_in[11];
  const float* bet = (const float*)d_in[12];
  float* out = (float*)d_out;

  char* ws = (char*)d_ws;
  int*   idx = (int*)ws;                                  // BN*16 ints (1 MB)
  float* Q   = (float*)(ws + (size_t)BN * KNB * 4);       // BN*384 floats
  float* Kt  = Q  + (size_t)BN * CC * 3;
  float* U   = Kt + (size_t)BN * CC * 3;
  float* qn  = U  + (size_t)BN * CC * 3;
  float* kn  = qn + BN;

  knn_kernel<<<BN/4, 256, 0, stream>>>(x, idx);
  vn_gemm_mfma<<<dim3((BN*3)/64, 3), 256, 0, stream>>>(v, Wq, Wk, Wu, Q, Kt, U);
  norms_kernel<<<BN/4, 256, 0, stream>>>(Q, Kt, qn, kn);
  attn_edge_kernel<<<BN/16, 256, 0, stream>>>(x, idx, Q, Kt, U, qn, kn,
                                              W1, b1, W2, b2, W3, b3, gam, bet, out);
}